// Round 1
// baseline (242.659 us; speedup 1.0000x reference)
//
#include <hip/hip_runtime.h>
#include <stdint.h>
#include <stddef.h>

// Problem dims (fixed by reference)
#define BB 8192
#define TT 26
#define VV 23
#define EE 100
#define HH 128
#define LL 64

typedef __attribute__((ext_vector_type(8))) short bf16x8;  // 8 bf16 = 4 VGPRs
typedef __attribute__((ext_vector_type(4))) float f32x4;   // MFMA 16x16 C/D

#define MFMA(a, b, c) __builtin_amdgcn_mfma_f32_16x16x32_bf16((a), (b), (c), 0, 0, 0)

// ---------------- workspace layout (bytes) ----------------
// GRU Whh B-frags:   24 ct * 4 kc * 1024B
#define OFF_GRUW   0ull                  // size 98304
// one-hot table B-frags (emb@gru_wih^T + gru_bih), K=32 (vocab): 24 ct * 1024B
#define OFF_TBL    98304ull              // size 24576
// LSTM fused W B-frags: rows 448 (4 gates x 112), K=256 (y:128 | h_l:128) -> 28 ct * 8 kc * 1024B
#define OFF_LSTMW  122880ull             // size 229376
// out_w B-frags: 2 ct * 4 kc * 1024B
#define OFF_OUTW   352256ull             // size 8192
// fc_z_w B-frags: 8 ct * 2 kc * 1024B
#define OFF_FCZW   360448ull             // size 16384
// fused LSTM bias (bih+bhh), padded 4*112 fp32
#define OFF_LBIAS  376832ull             // size 1792
// y (GRU output) in A-frag layout: 512 btile * 26 t * 4 kc * 1024B bf16
#define OFF_Y      379904ull             // size 54525952  (total ~52.4 MiB)

__device__ __forceinline__ unsigned short f2bf(float f) {
  union { float f; unsigned u; } v; v.f = f;
  unsigned u = v.u;
  return (unsigned short)((u + 0x7FFFu + ((u >> 16) & 1u)) >> 16);  // RNE
}
__device__ __forceinline__ float sigm(float x) { return 1.0f / (1.0f + __expf(-x)); }
__device__ __forceinline__ float tanh_(float x) { return 2.0f / (1.0f + __expf(-2.0f * x)) - 1.0f; }

// =====================================================================
// K0: weight swizzle into MFMA B-fragment order (bf16), table build.
// B-frag (ct,kc): lane holds B[k][n] with n = ct*16 + (lane&15),
// k = kc*32 + ((lane>>4)&3)*8 + j  (j = element 0..7). A-frags use the
// mirrored k ordering, so the contraction is layout-permutation-safe.
// =====================================================================
__global__ __launch_bounds__(256) void prep_kernel(
    const float* __restrict__ emb, const float* __restrict__ fc_z_w,
    const float* __restrict__ gru_wih, const float* __restrict__ gru_whh,
    const float* __restrict__ gru_bih,
    const float* __restrict__ lstm_wih, const float* __restrict__ lstm_whh,
    const float* __restrict__ lstm_bih, const float* __restrict__ lstm_bhh,
    const float* __restrict__ out_w,
    char* __restrict__ ws)
{
  int e = blockIdx.x * 256 + threadIdx.x;

  // ---- GRU Whh (384x128) ----
  if (e < 49152) {
    int j = e & 7, lane = (e >> 3) & 63, kc = (e >> 9) & 3, ct = e >> 11;
    int n = ct * 16 + (lane & 15);
    int k = kc * 32 + ((lane >> 4) & 3) * 8 + j;
    *(unsigned short*)(ws + OFF_GRUW + (size_t)e * 2) = f2bf(gru_whh[n * HH + k]);
    return;
  }
  e -= 49152;
  // ---- one-hot table: tbl[k=vocab][n=0..383] = emb[k]@gru_wih[n] + bih[n] ----
  if (e < 12288) {
    int j = e & 7, lane = (e >> 3) & 63, ct = e >> 9;
    int n = ct * 16 + (lane & 15);
    int k = ((lane >> 4) & 3) * 8 + j;   // vocab 0..31 (pad >=23 -> 0)
    float v = 0.0f;
    if (k < VV) {
      float s = gru_bih[n];
      for (int m = 0; m < EE; m++) s += emb[k * EE + m] * gru_wih[n * EE + m];
      v = s;
    }
    *(unsigned short*)(ws + OFF_TBL + (size_t)e * 2) = f2bf(v);
    return;
  }
  e -= 12288;
  // ---- LSTM fused W: row = 112*g + c (c<100 real), K = [y 0..127 | h_l 0..127] ----
  if (e < 114688) {
    int j = e & 7, lane = (e >> 3) & 63, kc = (e >> 9) & 7, ct = e >> 12;
    int row = ct * 16 + (lane & 15);
    int g = row / 112, c = row % 112;
    int q = (lane >> 4) & 3;
    float v = 0.0f;
    if (c < EE) {
      if (kc < 4) {
        int k = kc * 32 + q * 8 + j;            // y feature (H=128, all real)
        v = lstm_wih[(g * EE + c) * HH + k];
      } else {
        int k = (kc - 4) * 32 + q * 8 + j;      // h_l feature (E=100, pad->0)
        if (k < EE) v = lstm_whh[(g * EE + c) * EE + k];
      }
    }
    *(unsigned short*)(ws + OFF_LSTMW + (size_t)e * 2) = f2bf(v);
    return;
  }
  e -= 114688;
  // ---- out_w (23x100 -> 32 x 128 padded) ----
  if (e < 4096) {
    int j = e & 7, lane = (e >> 3) & 63, kc = (e >> 9) & 3, ct = e >> 11;
    int n = ct * 16 + (lane & 15);
    int k = kc * 32 + ((lane >> 4) & 3) * 8 + j;
    float v = (n < VV && k < EE) ? out_w[n * EE + k] : 0.0f;
    *(unsigned short*)(ws + OFF_OUTW + (size_t)e * 2) = f2bf(v);
    return;
  }
  e -= 4096;
  // ---- fc_z_w (128x64) ----
  if (e < 8192) {
    int j = e & 7, lane = (e >> 3) & 63, kc = (e >> 9) & 1, ct = e >> 10;
    int n = ct * 16 + (lane & 15);
    int k = kc * 32 + ((lane >> 4) & 3) * 8 + j;
    *(unsigned short*)(ws + OFF_FCZW + (size_t)e * 2) = f2bf(fc_z_w[n * LL + k]);
    return;
  }
  e -= 8192;
  // ---- fused LSTM bias (bih+bhh), padded ----
  if (e < 448) {
    int g = e / 112, c = e % 112;
    float v = (c < EE) ? (lstm_bih[g * EE + c] + lstm_bhh[g * EE + c]) : 0.0f;
    *(float*)(ws + OFF_LBIAS + (size_t)e * 4) = v;
  }
}

// =====================================================================
// K1: GRU scan. 512 blocks x 512 thr (8 waves), 16 batch rows/block.
// Wave w owns cols [16w,16w+16) of each gate (r,z,n). Weights reg-stationary.
// h: fp32 in regs (C-layout) + bf16 in double-buffered LDS (A-frags).
// Emits y_t in A-frag layout (bf16) for K2.
// =====================================================================
__global__ __launch_bounds__(512, 4) void gru_kernel(
    const float* __restrict__ z, const int* __restrict__ x_in,
    const float* __restrict__ fc_z_b, const float* __restrict__ gru_bhh,
    char* __restrict__ ws)
{
  __shared__ unsigned short h_lds[2][16 * 136];   // stride 136 (+8 pad)
  __shared__ unsigned char idx_lds[TT * 16];
  const int tid  = threadIdx.x;
  const int wv   = tid >> 6;
  const int lane = tid & 63;
  const int l15  = lane & 15;
  const int q    = (lane >> 4) & 3;
  const int blk  = blockIdx.x;

  for (int i = tid; i < TT * 16; i += 512) {
    int t = i >> 4, r = i & 15;
    idx_lds[i] = (unsigned char)x_in[(blk * 16 + r) * TT + t];
  }

  // stationary weight fragments
  bf16x8 gw[3][4], tw[3];
#pragma unroll
  for (int g = 0; g < 3; g++) {
    int ct = g * 8 + wv;
#pragma unroll
    for (int kc = 0; kc < 4; kc++)
      gw[g][kc] = *(const bf16x8*)(ws + OFF_GRUW + (size_t)(ct * 4 + kc) * 1024 + lane * 16);
    tw[g] = *(const bf16x8*)(ws + OFF_TBL + (size_t)ct * 1024 + lane * 16);
  }
  const int col = wv * 16 + l15;
  const float b_r = gru_bhh[0 * HH + col];
  const float b_z = gru_bhh[1 * HH + col];
  const float b_n = gru_bhh[2 * HH + col];

  // h0 = tanh(z @ fc_z_w^T + fc_z_b) via MFMA
  float h[4];
  {
    bf16x8 fw0 = *(const bf16x8*)(ws + OFF_FCZW + (size_t)(wv * 2 + 0) * 1024 + lane * 16);
    bf16x8 fw1 = *(const bf16x8*)(ws + OFF_FCZW + (size_t)(wv * 2 + 1) * 1024 + lane * 16);
    const float* zp = z + (size_t)(blk * 16 + l15) * LL + q * 8;
    f32x4 z0 = *(const f32x4*)(zp);
    f32x4 z1 = *(const f32x4*)(zp + 4);
    f32x4 z2 = *(const f32x4*)(zp + 32);
    f32x4 z3 = *(const f32x4*)(zp + 36);
    bf16x8 za0, za1;
#pragma unroll
    for (int j = 0; j < 4; j++) {
      za0[j]     = (short)f2bf(z0[j]);
      za0[4 + j] = (short)f2bf(z1[j]);
      za1[j]     = (short)f2bf(z2[j]);
      za1[4 + j] = (short)f2bf(z3[j]);
    }
    float fzb = fc_z_b[col];
    f32x4 acc = {fzb, fzb, fzb, fzb};
    acc = MFMA(za0, fw0, acc);
    acc = MFMA(za1, fw1, acc);
#pragma unroll
    for (int i = 0; i < 4; i++) {
      h[i] = tanh_(acc[i]);
      h_lds[0][(q * 4 + i) * 136 + col] = f2bf(h[i]);
    }
  }
  __syncthreads();

  int cur = 0;
  for (int t = 0; t < TT; t++) {
    // A-frags of h (bf16) from LDS
    bf16x8 a[4];
#pragma unroll
    for (int kc = 0; kc < 4; kc++)
      a[kc] = *(const bf16x8*)((const char*)h_lds[cur] + (size_t)l15 * 272 + kc * 64 + q * 16);

    // one-hot A-frag selects table row idx[b]
    int iv = idx_lds[t * 16 + l15];
    bf16x8 oh;
#pragma unroll
    for (int j = 0; j < 8; j++)
      oh[j] = (short)((iv == q * 8 + j) ? 0x3F80 : 0);

    f32x4 ar  = {b_r, b_r, b_r, b_r};
    f32x4 az  = {b_z, b_z, b_z, b_z};
    f32x4 ahn = {b_n, b_n, b_n, b_n};
    f32x4 axn = {0.0f, 0.0f, 0.0f, 0.0f};
#pragma unroll
    for (int kc = 0; kc < 4; kc++) {
      ar  = MFMA(a[kc], gw[0][kc], ar);
      az  = MFMA(a[kc], gw[1][kc], az);
      ahn = MFMA(a[kc], gw[2][kc], ahn);
    }
    ar  = MFMA(oh, tw[0], ar);
    az  = MFMA(oh, tw[1], az);
    axn = MFMA(oh, tw[2], axn);

    int nb = cur ^ 1;
#pragma unroll
    for (int i = 0; i < 4; i++) {
      float r  = sigm(ar[i]);
      float zg = sigm(az[i]);
      float n  = tanh_(axn[i] + r * ahn[i]);
      h[i] = (1.0f - zg) * n + zg * h[i];
      h_lds[nb][(q * 4 + i) * 136 + col] = f2bf(h[i]);
    }
    __syncthreads();
    // export y_t in A-frag layout (waves 0..3, kc = wv)
    if (wv < 4) {
      bf16x8 yv = *(const bf16x8*)((const char*)h_lds[nb] + (size_t)l15 * 272 + wv * 64 + q * 16);
      *(bf16x8*)(ws + OFF_Y + ((size_t)(blk * TT + t) * 4 + wv) * 1024 + lane * 16) = yv;
    }
    cur = nb;
  }
}

// =====================================================================
// K2: LSTM scan + logits. 256 blocks x 448 thr (7 waves), 32 rows/block.
// Wave w owns cols [16w,16w+16) of each gate (i,f,g,o); Ep=112 -> 7 tiles.
// Fused K=256 matmul (y || h_l). c fp32 in regs; h_l bf16 in dbuf LDS.
// Logits fused per step on waves 0..3. Rolling y prefetch.
// =====================================================================
__global__ __launch_bounds__(448) void lstm_kernel(
    const float* __restrict__ out_b, char* __restrict__ ws,
    float* __restrict__ out)
{
  __shared__ unsigned short h_lds[2][32 * 136];
  const int tid  = threadIdx.x;
  const int wv   = tid >> 6;        // 0..6
  const int lane = tid & 63;
  const int l15  = lane & 15;
  const int q    = (lane >> 4) & 3;
  const int blk  = blockIdx.x;      // 0..255

  for (int i = tid; i < 2 * 32 * 136; i += 448)
    ((unsigned short*)h_lds)[i] = 0;

  bf16x8 lw[4][8];
#pragma unroll
  for (int g = 0; g < 4; g++) {
    int ct = g * 7 + wv;
#pragma unroll
    for (int kc = 0; kc < 8; kc++)
      lw[g][kc] = *(const bf16x8*)(ws + OFF_LSTMW + (size_t)(ct * 8 + kc) * 1024 + lane * 16);
  }
  const int col = wv * 16 + l15;
  const float* lb = (const float*)(ws + OFF_LBIAS);
  const float b_i = lb[0 * 112 + col];
  const float b_f = lb[1 * 112 + col];
  const float b_g = lb[2 * 112 + col];
  const float b_o = lb[3 * 112 + col];

  // logits weights on waves 0..3: wave -> (row-tile, col-tile)
  bf16x8 ow[4];
  const int lrt = wv >> 1, lct = wv & 1, lcol = lct * 16 + l15;
  float ob = 0.0f;
  if (wv < 4) {
#pragma unroll
    for (int kc = 0; kc < 4; kc++)
      ow[kc] = *(const bf16x8*)(ws + OFF_OUTW + (size_t)(lct * 4 + kc) * 1024 + lane * 16);
    if (lcol < VV) ob = out_b[lcol];
  }

  float c0[4] = {0, 0, 0, 0}, c1[4] = {0, 0, 0, 0};
  __syncthreads();

  bf16x8 ya0[4], ya1[4];
#pragma unroll
  for (int kc = 0; kc < 4; kc++)
    ya0[kc] = *(const bf16x8*)(ws + OFF_Y + ((size_t)((blk * 2 + 0) * TT + 0) * 4 + kc) * 1024 + lane * 16);

  int cur = 0;
  for (int t = 0; t < TT; t++) {
    int nb = cur ^ 1;
    // prefetch rt=1 y
#pragma unroll
    for (int kc = 0; kc < 4; kc++)
      ya1[kc] = *(const bf16x8*)(ws + OFF_Y + ((size_t)((blk * 2 + 1) * TT + t) * 4 + kc) * 1024 + lane * 16);

    // ---------- rt = 0 ----------
    {
      bf16x8 ha[4];
#pragma unroll
      for (int kc = 0; kc < 4; kc++)
        ha[kc] = *(const bf16x8*)((const char*)h_lds[cur] + (size_t)l15 * 272 + kc * 64 + q * 16);
      f32x4 ai = {b_i, b_i, b_i, b_i};
      f32x4 af = {b_f, b_f, b_f, b_f};
      f32x4 ag = {b_g, b_g, b_g, b_g};
      f32x4 ao = {b_o, b_o, b_o, b_o};
#pragma unroll
      for (int kc = 0; kc < 4; kc++) {
        ai = MFMA(ya0[kc], lw[0][kc], ai);
        af = MFMA(ya0[kc], lw[1][kc], af);
        ag = MFMA(ya0[kc], lw[2][kc], ag);
        ao = MFMA(ya0[kc], lw[3][kc], ao);
      }
#pragma unroll
      for (int kc = 0; kc < 4; kc++) {
        ai = MFMA(ha[kc], lw[0][kc + 4], ai);
        af = MFMA(ha[kc], lw[1][kc + 4], af);
        ag = MFMA(ha[kc], lw[2][kc + 4], ag);
        ao = MFMA(ha[kc], lw[3][kc + 4], ao);
      }
#pragma unroll
      for (int i = 0; i < 4; i++) {
        float ii = sigm(ai[i]), ff = sigm(af[i]);
        float gg = tanh_(ag[i]), oo = sigm(ao[i]);
        float cn = ff * c0[i] + ii * gg;
        c0[i] = cn;
        h_lds[nb][(q * 4 + i) * 136 + col] = f2bf(oo * tanh_(cn));
      }
    }
    // prefetch next-t rt=0 y (clamped; redundant at t=TT-1)
    {
      int tn = (t + 1 < TT) ? (t + 1) : (TT - 1);
#pragma unroll
      for (int kc = 0; kc < 4; kc++)
        ya0[kc] = *(const bf16x8*)(ws + OFF_Y + ((size_t)((blk * 2 + 0) * TT + tn) * 4 + kc) * 1024 + lane * 16);
    }
    // ---------- rt = 1 ----------
    {
      bf16x8 ha[4];
#pragma unroll
      for (int kc = 0; kc < 4; kc++)
        ha[kc] = *(const bf16x8*)((const char*)h_lds[cur] + (size_t)(16 + l15) * 272 + kc * 64 + q * 16);
      f32x4 ai = {b_i, b_i, b_i, b_i};
      f32x4 af = {b_f, b_f, b_f, b_f};
      f32x4 ag = {b_g, b_g, b_g, b_g};
      f32x4 ao = {b_o, b_o, b_o, b_o};
#pragma unroll
      for (int kc = 0; kc < 4; kc++) {
        ai = MFMA(ya1[kc], lw[0][kc], ai);
        af = MFMA(ya1[kc], lw[1][kc], af);
        ag = MFMA(ya1[kc], lw[2][kc], ag);
        ao = MFMA(ya1[kc], lw[3][kc], ao);
      }
#pragma unroll
      for (int kc = 0; kc < 4; kc++) {
        ai = MFMA(ha[kc], lw[0][kc + 4], ai);
        af = MFMA(ha[kc], lw[1][kc + 4], af);
        ag = MFMA(ha[kc], lw[2][kc + 4], ag);
        ao = MFMA(ha[kc], lw[3][kc + 4], ao);
      }
#pragma unroll
      for (int i = 0; i < 4; i++) {
        float ii = sigm(ai[i]), ff = sigm(af[i]);
        float gg = tanh_(ag[i]), oo = sigm(ao[i]);
        float cn = ff * c1[i] + ii * gg;
        c1[i] = cn;
        h_lds[nb][(16 + q * 4 + i) * 136 + col] = f2bf(oo * tanh_(cn));
      }
    }
    __syncthreads();
    // ---------- logits for step t (waves 0..3) ----------
    if (wv < 4) {
      bf16x8 ha2[4];
#pragma unroll
      for (int kc = 0; kc < 4; kc++)
        ha2[kc] = *(const bf16x8*)((const char*)h_lds[nb] + (size_t)(lrt * 16 + l15) * 272 + kc * 64 + q * 16);
      f32x4 acc = {ob, ob, ob, ob};
#pragma unroll
      for (int kc = 0; kc < 4; kc++)
        acc = MFMA(ha2[kc], ow[kc], acc);
      if (lcol < VV) {
#pragma unroll
        for (int i = 0; i < 4; i++) {
          int rowg = blk * 32 + lrt * 16 + q * 4 + i;
          out[((size_t)rowg * TT + t) * VV + lcol] = acc[i];
        }
      }
    }
    cur = nb;
  }
}

extern "C" void kernel_launch(void* const* d_in, const int* in_sizes, int n_in,
                              void* d_out, int out_size, void* d_ws, size_t ws_size,
                              hipStream_t stream) {
  (void)in_sizes; (void)n_in; (void)out_size; (void)ws_size;
  const float* z        = (const float*)d_in[0];
  const int*   x_in     = (const int*)  d_in[1];
  const float* emb      = (const float*)d_in[2];
  const float* fc_z_w   = (const float*)d_in[3];
  const float* fc_z_b   = (const float*)d_in[4];
  const float* gru_wih  = (const float*)d_in[5];
  const float* gru_whh  = (const float*)d_in[6];
  const float* gru_bih  = (const float*)d_in[7];
  const float* gru_bhh  = (const float*)d_in[8];
  const float* lstm_wih = (const float*)d_in[9];
  const float* lstm_whh = (const float*)d_in[10];
  const float* lstm_bih = (const float*)d_in[11];
  const float* lstm_bhh = (const float*)d_in[12];
  const float* out_w    = (const float*)d_in[13];
  const float* out_b    = (const float*)d_in[14];
  char*  ws  = (char*)d_ws;
  float* out = (float*)d_out;

  // total prep elements: 49152+12288+114688+4096+8192+448 = 188864 -> 738 blocks
  prep_kernel<<<738, 256, 0, stream>>>(emb, fc_z_w, gru_wih, gru_whh, gru_bih,
                                       lstm_wih, lstm_whh, lstm_bih, lstm_bhh,
                                       out_w, ws);
  gru_kernel<<<512, 512, 0, stream>>>(z, x_in, fc_z_b, gru_bhh, ws);
  lstm_kernel<<<256, 448, 0, stream>>>(out_b, ws, out);
}